// Round 2
// baseline (193.218 us; speedup 1.0000x reference)
//
#include <hip/hip_runtime.h>
#include <math.h>

#define BM 32
#define BK 64
#define SPAD 112          // padded sample-column count (100 -> 112)
#define LDA 68            // padded LDS row stride in floats (64 + 4)
#define NTHREADS 256

// ws[0] = sum of per-token losses, ws[1] = valid count (as float)
__global__ __launch_bounds__(NTHREADS, 4)
void ssce_main(const float* __restrict__ pred,
               const int*   __restrict__ labels,
               const float* __restrict__ proj,
               const float* __restrict__ bias,
               const int*   __restrict__ samples,
               float* __restrict__ ws,
               int Btot, int D, int V, int S, float logV1)
{
    __shared__ float sA[BM * LDA];        //  8704 B  pred tile [32][68]
    __shared__ float sQ[SPAD * LDA];      // 30464 B  proj[samples] tile; reused for scores
    __shared__ float sLabelScore[BM];
    __shared__ float sBiasS[SPAD];
    __shared__ int   sSamp[SPAD];
    __shared__ int   sLabels[BM];

    const int tid  = threadIdx.x;
    const int tn   = tid & 15;            // 0..15
    const int tm   = tid >> 4;            // 0..15
    const int lane = tid & 63;
    const int w    = tid >> 6;            // wave 0..3
    const int rowBase = blockIdx.x * BM;

    // ---- stage samples / bias / labels ----
    if (tid < SPAD) {
        int s = (tid < S) ? samples[tid] : -1;
        sSamp[tid]  = s;
        sBiasS[tid] = (s >= 0) ? bias[s] : 0.0f;
    }
    if (tid < BM) {
        int gr = rowBase + tid;
        sLabels[tid] = (gr < Btot) ? labels[gr] : -100;
    }
    __syncthreads();

    // ---- per-thread staging pointers ----
    int rA0 = min(rowBase + tm,      Btot - 1);
    int rA1 = min(rowBase + tm + 16, Btot - 1);
    const float* aSrc0 = pred + (size_t)rA0 * D + tn * 4;
    const float* aSrc1 = pred + (size_t)rA1 * D + tn * 4;
    float* aDst0 = &sA[ tm       * LDA + tn * 4];
    float* aDst1 = &sA[(tm + 16) * LDA + tn * 4];

    // Q tile: thread stages sample-rows s = tm + 16*i, i=0..6 (clamped; padded
    // rows hold garbage from proj row 0 but their columns are never read)
    const float* qSrc[7];
    float*       qDst[7];
    #pragma unroll
    for (int i = 0; i < 7; ++i) {
        int s  = tm + 16 * i;
        int sm = (s < S) ? sSamp[s] : 0;
        if (sm < 0) sm = 0;
        qSrc[i] = proj + (size_t)sm * D + tn * 4;
        qDst[i] = &sQ[s * LDA + tn * 4];
    }

    // label-dot pointers: wave w owns local rows w*8 .. w*8+7
    const float* lPtr[8];
    float lFlag[8];
    #pragma unroll
    for (int j = 0; j < 8; ++j) {
        int lab = sLabels[w * 8 + j];
        lPtr[j]  = proj + (size_t)(lab >= 0 ? lab : 0) * D + lane;
        lFlag[j] = (lab >= 0) ? 1.0f : 0.0f;
    }

    float acc[2][7];
    #pragma unroll
    for (int i = 0; i < 2; ++i)
        #pragma unroll
        for (int j = 0; j < 7; ++j) acc[i][j] = 0.0f;
    float lpart[8];
    #pragma unroll
    for (int j = 0; j < 8; ++j) lpart[j] = 0.0f;

    const int r0 = 2 * tm, r1 = 2 * tm + 1;
    const int nChunks = D / BK;           // 768/64 = 12

    // ---- prologue: prefetch chunk 0 into registers ----
    float4 pa0 = *(const float4*)(aSrc0);
    float4 pa1 = *(const float4*)(aSrc1);
    float4 pq[7];
    #pragma unroll
    for (int i = 0; i < 7; ++i) pq[i] = *(const float4*)(qSrc[i]);

    for (int ck = 0; ck < nChunks; ++ck) {
        const int k0 = ck * BK;
        __syncthreads();                  // previous compute done; LDS reusable
        // ---- write prefetched registers to LDS ----
        *(float4*)aDst0 = pa0;
        *(float4*)aDst1 = pa1;
        #pragma unroll
        for (int i = 0; i < 7; ++i) *(float4*)qDst[i] = pq[i];
        __syncthreads();                  // tiles visible

        // ---- label-row loads for THIS chunk (issued first so their wait
        //      doesn't drain the prefetch queue) ----
        float pl[8];
        #pragma unroll
        for (int j = 0; j < 8; ++j) pl[j] = lPtr[j][k0] * lFlag[j];

        // ---- prefetch NEXT chunk into registers (hidden under GEMM) ----
        if (ck + 1 < nChunks) {
            const int k1 = k0 + BK;
            pa0 = *(const float4*)(aSrc0 + k1);
            pa1 = *(const float4*)(aSrc1 + k1);
            #pragma unroll
            for (int i = 0; i < 7; ++i) pq[i] = *(const float4*)(qSrc[i] + k1);
        }

        // ---- register-blocked GEMM: 2 rows x 7 cols ----
        #pragma unroll 4
        for (int kq = 0; kq < BK / 4; ++kq) {
            float4 a0 = *(const float4*)&sA[r0 * LDA + kq * 4];
            float4 a1 = *(const float4*)&sA[r1 * LDA + kq * 4];
            #pragma unroll
            for (int j = 0; j < 7; ++j) {
                float4 b = *(const float4*)&sQ[(tn + 16 * j) * LDA + kq * 4];
                acc[0][j] += a0.x * b.x + a0.y * b.y + a0.z * b.z + a0.w * b.w;
                acc[1][j] += a1.x * b.x + a1.y * b.y + a1.z * b.z + a1.w * b.w;
            }
        }
        // ---- label-dot FMAs against staged pred tile ----
        #pragma unroll
        for (int j = 0; j < 8; ++j)
            lpart[j] += sA[(w * 8 + j) * LDA + lane] * pl[j];
    }

    // ---- reduce label dots across the wave ----
    #pragma unroll
    for (int j = 0; j < 8; ++j) {
        float v = lpart[j];
        #pragma unroll
        for (int off = 32; off > 0; off >>= 1)
            v += __shfl_down(v, off);
        if (lane == 0) {
            int r   = w * 8 + j;
            int lab = sLabels[r];
            sLabelScore[r] = v + ((lab >= 0) ? bias[lab] : 0.0f);
        }
    }
    __syncthreads();                      // everyone done reading sQ & sA

    // ---- dump accumulators to LDS scores[32][113] (overlay on sQ) ----
    float* scores = sQ;
    #pragma unroll
    for (int i = 0; i < 2; ++i)
        #pragma unroll
        for (int j = 0; j < 7; ++j)
            scores[(2 * tm + i) * 113 + (tn + 16 * j)] = acc[i][j];
    __syncthreads();

    // ---- per-row softmax CE (threads 0..31, one row each) ----
    float pt = 0.0f, vc = 0.0f;
    if (tid < BM && rowBase + tid < Btot) {
        int  lab   = sLabels[tid];
        bool valid = (lab != -100);
        int  cnt   = 0;
        if (valid)
            for (int s = 0; s < S; ++s) cnt += (sSamp[s] == lab) ? 1 : 0;
        float corr = logV1 - __logf((float)(S - cnt));
        float ls   = sLabelScore[tid];
        float m    = ls;
        for (int s = 0; s < S; ++s) {
            float v = scores[tid * 113 + s] + sBiasS[s] + corr;
            if (valid && sSamp[s] == lab) v -= 1000000.0f;
            m = fmaxf(m, v);
        }
        float se = __expf(ls - m);
        for (int s = 0; s < S; ++s) {
            float v = scores[tid * 113 + s] + sBiasS[s] + corr;
            if (valid && sSamp[s] == lab) v -= 1000000.0f;
            se += __expf(v - m);
        }
        float per_tok = m - ls + __logf(se);
        if (valid) { pt = per_tok; vc = 1.0f; }
    }
    // ---- block reduce in wave 0 (lanes >=32 hold zeros) ----
    if (tid < 64) {
        #pragma unroll
        for (int off = 32; off > 0; off >>= 1) {
            pt += __shfl_down(pt, off);
            vc += __shfl_down(vc, off);
        }
        if (tid == 0) {
            atomicAdd(&ws[0], pt);
            atomicAdd(&ws[1], vc);
        }
    }
}

__global__ void ssce_final(const float* __restrict__ ws, float* __restrict__ out)
{
    out[0] = ws[0] / fmaxf(ws[1], 1.0f);
}

extern "C" void kernel_launch(void* const* d_in, const int* in_sizes, int n_in,
                              void* d_out, int out_size, void* d_ws, size_t ws_size,
                              hipStream_t stream)
{
    const float* pred    = (const float*)d_in[0];
    const int*   labels  = (const int*)  d_in[1];
    const float* proj    = (const float*)d_in[2];
    const float* bias    = (const float*)d_in[3];
    const int*   samples = (const int*)  d_in[4];

    const int B = in_sizes[1];            // labels count
    const int V = in_sizes[3];            // bias count = n_classes
    const int S = in_sizes[4];            // num samples
    const int D = in_sizes[0] / B;        // feature dim

    float logV1 = logf((float)(V - 1));
    float* ws = (float*)d_ws;

    hipMemsetAsync(d_ws, 0, 2 * sizeof(float), stream);

    const int grid = (B + BM - 1) / BM;
    ssce_main<<<grid, NTHREADS, 0, stream>>>(pred, labels, proj, bias, samples,
                                             ws, B, D, V, S, logV1);
    ssce_final<<<1, 1, 0, stream>>>(ws, (float*)d_out);
}

// Round 3
// 140.016 us; speedup vs baseline: 1.3800x; 1.3800x over previous
//
#include <hip/hip_runtime.h>
#include <math.h>

#define BM 32
#define BK 64
#define SPAD 112          // padded sample-column count (100 -> 112)
#define LDA 68            // padded LDS row stride in floats (64 + 4)
#define NTHREADS 256

// ws[0] = sum of per-token losses, ws[1] = valid count (as float)
__global__ __launch_bounds__(NTHREADS)
void ssce_main(const float* __restrict__ pred,
               const int*   __restrict__ labels,
               const float* __restrict__ proj,
               const float* __restrict__ bias,
               const int*   __restrict__ samples,
               float* __restrict__ ws,
               int Btot, int D, int V, int S, float logV1)
{
    __shared__ float sA[BM * LDA];        //  8704 B  pred tile [32][68]
    __shared__ float sQ[SPAD * LDA];      // 30464 B  proj[samples] tile; reused for scores
    __shared__ float sLabelScore[BM];
    __shared__ float sBiasS[SPAD];
    __shared__ int   sSamp[SPAD];
    __shared__ int   sLabels[BM];

    const int tid  = threadIdx.x;
    const int tn   = tid & 15;            // 0..15
    const int tm   = tid >> 4;            // 0..15
    const int lane = tid & 63;
    const int w    = tid >> 6;            // wave 0..3
    const int rowBase = blockIdx.x * BM;

    // ---- stage samples / bias / labels ----
    if (tid < SPAD) {
        int s = (tid < S) ? samples[tid] : -1;
        sSamp[tid]  = s;
        sBiasS[tid] = (s >= 0) ? bias[s] : 0.0f;
    }
    if (tid < BM) {
        int gr = rowBase + tid;
        sLabels[tid] = (gr < Btot) ? labels[gr] : -100;
    }
    __syncthreads();

    // ---- per-thread staging pointers ----
    int rA0 = min(rowBase + tm,      Btot - 1);
    int rA1 = min(rowBase + tm + 16, Btot - 1);
    const float* aSrc0 = pred + (size_t)rA0 * D + tn * 4;
    const float* aSrc1 = pred + (size_t)rA1 * D + tn * 4;
    float* aDst0 = &sA[ tm       * LDA + tn * 4];
    float* aDst1 = &sA[(tm + 16) * LDA + tn * 4];

    // Q tile: thread stages sample-rows s = tm + 16*i, i=0..6 (clamped; padded
    // rows hold garbage from proj row 0 but their columns are never read)
    const float* qSrc[7];
    float*       qDst[7];
    #pragma unroll
    for (int i = 0; i < 7; ++i) {
        int s  = tm + 16 * i;
        int sm = (s < S) ? sSamp[s] : 0;
        if (sm < 0) sm = 0;
        qSrc[i] = proj + (size_t)sm * D + tn * 4;
        qDst[i] = &sQ[s * LDA + tn * 4];
    }

    // label-dot rows: wave w owns local rows w*8 .. w*8+7. The label for a
    // given j is WAVE-UNIFORM -> readfirstlane puts the row base in SGPRs,
    // keeping the 8 row pointers out of the VGPR budget.
    int   labRow[8];
    float lFlag[8];
    #pragma unroll
    for (int j = 0; j < 8; ++j) {
        int lab   = __builtin_amdgcn_readfirstlane(sLabels[w * 8 + j]);
        labRow[j] = (lab >= 0) ? lab : 0;
        lFlag[j]  = (lab >= 0) ? 1.0f : 0.0f;
    }

    float acc[2][7];
    #pragma unroll
    for (int i = 0; i < 2; ++i)
        #pragma unroll
        for (int j = 0; j < 7; ++j) acc[i][j] = 0.0f;
    float lpart[8];
    #pragma unroll
    for (int j = 0; j < 8; ++j) lpart[j] = 0.0f;

    const int r0 = 2 * tm, r1 = 2 * tm + 1;
    const int nChunks = D / BK;           // 768/64 = 12

    // ---- prologue: prefetch chunk 0 into registers ----
    float4 pa0 = *(const float4*)(aSrc0);
    float4 pa1 = *(const float4*)(aSrc1);
    float4 pq[7];
    #pragma unroll
    for (int i = 0; i < 7; ++i) pq[i] = *(const float4*)(qSrc[i]);

    for (int ck = 0; ck < nChunks; ++ck) {
        const int k0 = ck * BK;
        __syncthreads();                  // previous compute done; LDS reusable
        // ---- write prefetched registers to LDS ----
        *(float4*)aDst0 = pa0;
        *(float4*)aDst1 = pa1;
        #pragma unroll
        for (int i = 0; i < 7; ++i) *(float4*)qDst[i] = pq[i];
        __syncthreads();                  // tiles visible

        // ---- label-row loads for THIS chunk (SGPR base + lane offset) ----
        float pl[8];
        #pragma unroll
        for (int j = 0; j < 8; ++j)
            pl[j] = proj[(size_t)labRow[j] * D + k0 + lane] * lFlag[j];

        // ---- prefetch NEXT chunk into registers (hidden under GEMM) ----
        if (ck + 1 < nChunks) {
            const int k1 = k0 + BK;
            pa0 = *(const float4*)(aSrc0 + k1);
            pa1 = *(const float4*)(aSrc1 + k1);
            #pragma unroll
            for (int i = 0; i < 7; ++i) pq[i] = *(const float4*)(qSrc[i] + k1);
        }

        // ---- register-blocked GEMM: 2 rows x 7 cols ----
        #pragma unroll 4
        for (int kq = 0; kq < BK / 4; ++kq) {
            float4 a0 = *(const float4*)&sA[r0 * LDA + kq * 4];
            float4 a1 = *(const float4*)&sA[r1 * LDA + kq * 4];
            #pragma unroll
            for (int j = 0; j < 7; ++j) {
                float4 b = *(const float4*)&sQ[(tn + 16 * j) * LDA + kq * 4];
                acc[0][j] += a0.x * b.x + a0.y * b.y + a0.z * b.z + a0.w * b.w;
                acc[1][j] += a1.x * b.x + a1.y * b.y + a1.z * b.z + a1.w * b.w;
            }
        }
        // ---- label-dot FMAs against staged pred tile ----
        #pragma unroll
        for (int j = 0; j < 8; ++j)
            lpart[j] += sA[(w * 8 + j) * LDA + lane] * pl[j];
    }

    // ---- reduce label dots across the wave ----
    #pragma unroll
    for (int j = 0; j < 8; ++j) {
        float v = lpart[j];
        #pragma unroll
        for (int off = 32; off > 0; off >>= 1)
            v += __shfl_down(v, off);
        if (lane == 0) {
            int r   = w * 8 + j;
            int lab = sLabels[r];
            sLabelScore[r] = v + ((lab >= 0) ? bias[lab] : 0.0f);
        }
    }
    __syncthreads();                      // everyone done reading sQ & sA

    // ---- dump accumulators to LDS scores[32][113] (overlay on sQ) ----
    float* scores = sQ;
    #pragma unroll
    for (int i = 0; i < 2; ++i)
        #pragma unroll
        for (int j = 0; j < 7; ++j)
            scores[(2 * tm + i) * 113 + (tn + 16 * j)] = acc[i][j];
    __syncthreads();

    // ---- per-row softmax CE (threads 0..31, one row each) ----
    float pt = 0.0f, vc = 0.0f;
    if (tid < BM && rowBase + tid < Btot) {
        int  lab   = sLabels[tid];
        bool valid = (lab != -100);
        int  cnt   = 0;
        if (valid)
            for (int s = 0; s < S; ++s) cnt += (sSamp[s] == lab) ? 1 : 0;
        float corr = logV1 - __logf((float)(S - cnt));
        float ls   = sLabelScore[tid];
        float m    = ls;
        for (int s = 0; s < S; ++s) {
            float v = scores[tid * 113 + s] + sBiasS[s] + corr;
            if (valid && sSamp[s] == lab) v -= 1000000.0f;
            m = fmaxf(m, v);
        }
        float se = __expf(ls - m);
        for (int s = 0; s < S; ++s) {
            float v = scores[tid * 113 + s] + sBiasS[s] + corr;
            if (valid && sSamp[s] == lab) v -= 1000000.0f;
            se += __expf(v - m);
        }
        float per_tok = m - ls + __logf(se);
        if (valid) { pt = per_tok; vc = 1.0f; }
    }
    // ---- block reduce in wave 0 (lanes >=32 hold zeros) ----
    if (tid < 64) {
        #pragma unroll
        for (int off = 32; off > 0; off >>= 1) {
            pt += __shfl_down(pt, off);
            vc += __shfl_down(vc, off);
        }
        if (tid == 0) {
            atomicAdd(&ws[0], pt);
            atomicAdd(&ws[1], vc);
        }
    }
}

__global__ void ssce_final(const float* __restrict__ ws, float* __restrict__ out)
{
    out[0] = ws[0] / fmaxf(ws[1], 1.0f);
}

extern "C" void kernel_launch(void* const* d_in, const int* in_sizes, int n_in,
                              void* d_out, int out_size, void* d_ws, size_t ws_size,
                              hipStream_t stream)
{
    const float* pred    = (const float*)d_in[0];
    const int*   labels  = (const int*)  d_in[1];
    const float* proj    = (const float*)d_in[2];
    const float* bias    = (const float*)d_in[3];
    const int*   samples = (const int*)  d_in[4];

    const int B = in_sizes[1];            // labels count
    const int V = in_sizes[3];            // bias count = n_classes
    const int S = in_sizes[4];            // num samples
    const int D = in_sizes[0] / B;        // feature dim

    float logV1 = logf((float)(V - 1));
    float* ws = (float*)d_ws;

    hipMemsetAsync(d_ws, 0, 2 * sizeof(float), stream);

    const int grid = (B + BM - 1) / BM;
    ssce_main<<<grid, NTHREADS, 0, stream>>>(pred, labels, proj, bias, samples,
                                             ws, B, D, V, S, logV1);
    ssce_final<<<1, 1, 0, stream>>>(ws, (float*)d_out);
}

// Round 4
// 79.273 us; speedup vs baseline: 2.4374x; 1.7663x over previous
//
#include <hip/hip_runtime.h>
#include <math.h>

#define BM 32
#define SPAD 112            // padded sample count (100 -> 7*16)
#define LDA 68              // padded LDS row stride (f32), 2-way-free on reads
#define NTHREADS 256

typedef __attribute__((ext_vector_type(8))) short short8;   // 8 bf16
typedef __attribute__((ext_vector_type(4))) float f32x4;

__device__ __forceinline__ unsigned short f2bf(float f) {
    unsigned int u = __float_as_uint(f);
    unsigned int r = u + 0x7fffu + ((u >> 16) & 1u);   // RNE (no NaN in data)
    return (unsigned short)(r >> 16);
}

// gather proj[samples] -> bf16 [SPAD][D] in workspace
__global__ void ssce_qprep(const float* __restrict__ proj,
                           const int*   __restrict__ samples,
                           unsigned short* __restrict__ Qb, int D, int S)
{
    int s   = blockIdx.x;                       // 0..SPAD-1
    int row = samples[s < S ? s : S - 1];       // clamp pads (never read)
    const float* src = proj + (size_t)row * D;
    unsigned short* dst = Qb + (size_t)s * D;
    for (int e = threadIdx.x; e < D; e += blockDim.x)
        dst[e] = f2bf(src[e]);
}

// ws[0] = loss sum, ws[1] = valid count
__global__ __launch_bounds__(NTHREADS)
void ssce_main(const float* __restrict__ pred,
               const int*   __restrict__ labels,
               const float* __restrict__ proj,
               const float* __restrict__ bias,
               const int*   __restrict__ samples,
               const unsigned short* __restrict__ Qb,
               float* __restrict__ ws,
               int Btot, int D, int S, float logV1)
{
    __shared__ float sA[2][BM][LDA];     // 17408 B, double-buffered pred tile
    __shared__ float sLabelScore[BM];
    __shared__ float sBiasS[SPAD];
    __shared__ int   sSamp[SPAD];
    __shared__ int   sLabels[BM];

    const int tid  = threadIdx.x;
    const int lane = tid & 63;
    const int w    = tid >> 6;           // wave 0..3
    const int l16  = lane & 15;
    const int lg   = lane >> 4;          // 0..3
    const int rg   = w & 1;              // row-group (16 rows)
    const int half = w >> 1;             // col-half
    const int ct0  = half * 3;           // tiles 0..3 or 3..6 (tile 3 dup, benign)
    const int rowBase = blockIdx.x * BM;

    if (tid < SPAD) {
        int s = (tid < S) ? samples[tid] : -1;
        sSamp[tid]  = s;
        sBiasS[tid] = (s >= 0) ? bias[s] : 0.0f;
    }
    if (tid < BM) {
        int gr = rowBase + tid;
        sLabels[tid] = (gr < Btot) ? labels[gr] : -100;
    }
    __syncthreads();

    // label rows are wave-uniform -> SGPR
    int   labRow[8];
    float lFlag[8];
    #pragma unroll
    for (int j = 0; j < 8; ++j) {
        int lab   = __builtin_amdgcn_readfirstlane(sLabels[w * 8 + j]);
        labRow[j] = (lab >= 0) ? lab : 0;
        lFlag[j]  = (lab >= 0) ? 1.0f : 0.0f;
    }

    // staging map: thread stages 8 consecutive f32 of one row
    const int sr   = tid & 31;           // row 0..31
    const int sseg = tid >> 5;           // 0..7 (8 floats each)
    const float* aSrc = pred + (size_t)min(rowBase + sr, Btot - 1) * D + sseg * 8;
    float* aDst = &sA[0][sr][sseg * 8];  // buffer 0; buffer 1 via +BM*LDA

    f32x4 acc[4] = {{0.f,0.f,0.f,0.f},{0.f,0.f,0.f,0.f},
                    {0.f,0.f,0.f,0.f},{0.f,0.f,0.f,0.f}};
    float lpart[8];
    #pragma unroll
    for (int j = 0; j < 8; ++j) lpart[j] = 0.0f;

    const int nCh = D / 64;              // 12

    // prologue prefetch
    float4 pa0 = *(const float4*)(aSrc);
    float4 pa1 = *(const float4*)(aSrc + 4);

    for (int ck = 0; ck < nCh; ++ck) {
        const int cur = ck & 1;
        const int kk  = ck * 64;
        // write prefetched pred chunk
        float* dst = aDst + cur * (BM * LDA);
        *(float4*)dst       = pa0;
        *(float4*)(dst + 4) = pa1;
        __syncthreads();                 // writes visible; old buffer free

        // prefetch next chunk (register, 8 VGPR)
        if (ck + 1 < nCh) {
            pa0 = *(const float4*)(aSrc + kk + 64);
            pa1 = *(const float4*)(aSrc + kk + 68);
        }

        // B fragments for both K-steps (L2-resident Qb), issued early
        short8 bf[2][4];
        #pragma unroll
        for (int ks = 0; ks < 2; ++ks)
            #pragma unroll
            for (int t = 0; t < 4; ++t)
                bf[ks][t] = *(const short8*)(Qb +
                    (size_t)((ct0 + t) * 16 + l16) * D + kk + ks * 32 + lg * 8);

        // label-row gathers (f32, 64 lanes = 256 B contiguous per row)
        float pl[8];
        #pragma unroll
        for (int j = 0; j < 8; ++j)
            pl[j] = proj[(size_t)labRow[j] * D + kk + lane] * lFlag[j];

        // A fragments from LDS (f32) -> bf16, then MFMA
        const float* abuf = &sA[cur][0][0];
        #pragma unroll
        for (int ks = 0; ks < 2; ++ks) {
            const float* ap = abuf + (rg * 16 + l16) * LDA + ks * 32 + lg * 8;
            float4 af0 = *(const float4*)(ap);
            float4 af1 = *(const float4*)(ap + 4);
            short8 a8;
            a8[0] = (short)f2bf(af0.x); a8[1] = (short)f2bf(af0.y);
            a8[2] = (short)f2bf(af0.z); a8[3] = (short)f2bf(af0.w);
            a8[4] = (short)f2bf(af1.x); a8[5] = (short)f2bf(af1.y);
            a8[6] = (short)f2bf(af1.z); a8[7] = (short)f2bf(af1.w);
            #pragma unroll
            for (int t = 0; t < 4; ++t)
                acc[t] = __builtin_amdgcn_mfma_f32_16x16x32_bf16(
                             a8, bf[ks][t], acc[t], 0, 0, 0);
        }

        // label dot (full f32)
        #pragma unroll
        for (int j = 0; j < 8; ++j)
            lpart[j] += abuf[(w * 8 + j) * LDA + lane] * pl[j];
    }

    // reduce label dots across wave
    #pragma unroll
    for (int j = 0; j < 8; ++j) {
        float v = lpart[j];
        #pragma unroll
        for (int off = 32; off > 0; off >>= 1) v += __shfl_down(v, off);
        if (lane == 0) {
            int r   = w * 8 + j;
            int lab = sLabels[r];
            sLabelScore[r] = v + ((lab >= 0) ? bias[lab] : 0.0f);
        }
    }
    __syncthreads();                     // all LDS reads of sA done

    // scores overlay on sA: [32][113]
    float* scores = &sA[0][0][0];
    #pragma unroll
    for (int t = 0; t < 4; ++t)
        #pragma unroll
        for (int i = 0; i < 4; ++i) {
            int row = rg * 16 + lg * 4 + i;
            int col = (ct0 + t) * 16 + l16;
            scores[row * 113 + col] = acc[t][i];   // tile-3 dup write: same value
        }
    __syncthreads();

    // per-row softmax CE (threads 0..31)
    float pt = 0.0f, vc = 0.0f;
    if (tid < BM && rowBase + tid < Btot) {
        int  lab   = sLabels[tid];
        bool valid = (lab != -100);
        int  cnt   = 0;
        if (valid)
            for (int s = 0; s < S; ++s) cnt += (sSamp[s] == lab) ? 1 : 0;
        float corr = logV1 - __logf((float)(S - cnt));
        float ls   = sLabelScore[tid];
        float m    = ls;
        for (int s = 0; s < S; ++s) {
            float v = scores[tid * 113 + s] + sBiasS[s] + corr;
            if (valid && sSamp[s] == lab) v -= 1000000.0f;
            m = fmaxf(m, v);
        }
        float se = __expf(ls - m);
        for (int s = 0; s < S; ++s) {
            float v = scores[tid * 113 + s] + sBiasS[s] + corr;
            if (valid && sSamp[s] == lab) v -= 1000000.0f;
            se += __expf(v - m);
        }
        float per_tok = m - ls + __logf(se);
        if (valid) { pt = per_tok; vc = 1.0f; }
    }
    if (tid < 64) {
        #pragma unroll
        for (int off = 32; off > 0; off >>= 1) {
            pt += __shfl_down(pt, off);
            vc += __shfl_down(vc, off);
        }
        if (tid == 0) {
            atomicAdd(&ws[0], pt);
            atomicAdd(&ws[1], vc);
        }
    }
}

__global__ void ssce_final(const float* __restrict__ ws, float* __restrict__ out)
{
    out[0] = ws[0] / fmaxf(ws[1], 1.0f);
}

extern "C" void kernel_launch(void* const* d_in, const int* in_sizes, int n_in,
                              void* d_out, int out_size, void* d_ws, size_t ws_size,
                              hipStream_t stream)
{
    const float* pred    = (const float*)d_in[0];
    const int*   labels  = (const int*)  d_in[1];
    const float* proj    = (const float*)d_in[2];
    const float* bias    = (const float*)d_in[3];
    const int*   samples = (const int*)  d_in[4];

    const int B = in_sizes[1];
    const int V = in_sizes[3];
    const int S = in_sizes[4];
    const int D = in_sizes[0] / B;        // 768

    float logV1 = logf((float)(V - 1));
    float* ws = (float*)d_ws;
    unsigned short* Qb = (unsigned short*)((char*)d_ws + 256);

    hipMemsetAsync(d_ws, 0, 2 * sizeof(float), stream);
    ssce_qprep<<<SPAD, 256, 0, stream>>>(proj, samples, Qb, D, S);

    const int grid = (B + BM - 1) / BM;   // 512
    ssce_main<<<grid, NTHREADS, 0, stream>>>(pred, labels, proj, bias, samples,
                                             Qb, ws, B, D, S, logV1);
    ssce_final<<<1, 1, 0, stream>>>(ws, (float*)d_out);
}